// Round 3
// baseline (186.305 us; speedup 1.0000x reference)
//
#include <hip/hip_runtime.h>

#define PP 16
#define DD 64
#define RR 32
#define KK 64
#define NBT 4096   // B*T

#define LOG2E 1.4426950408889634f
#define LN2   0.6931471805599453f
#define D2_CUT 25.0f   // keep pairs with d2 <= d2min + CUT; error <= omega_max*e^-25*ln2

static __device__ __forceinline__ float fast_log2(float x) { return __builtin_amdgcn_logf(x); }
static __device__ __forceinline__ float fast_exp2(float x) { return __builtin_amdgcn_exp2f(x); }
static __device__ __forceinline__ float fast_rcp(float x)  { return __builtin_amdgcn_rcpf(x); }

// Single fused kernel: per-block local prune (c identical per block -> identical
// dmin/pair set), then logits -> softmax -> mass -> pbar -> pruned JS sum.
// Writes partials[bt] with a PLAIN store: rounds 1-2 proved a single-address
// device atomicAdd from 4096 blocks costs ~25 us of far-atomic serialization.
__global__ __launch_bounds__(256) void sheaf_kernel(
    const float* __restrict__ m, const float* __restrict__ w,
    const float* __restrict__ p, const float* __restrict__ c,
    float* __restrict__ partials) {
    // Alias zone: sm_pl (phase 4/5) overlaps cT2 (bytes 0-8447, pre/phase 1) and
    // the staged m tile (bytes 8448-12543, phase 1). Lifetimes barrier-separated.
    __shared__ __align__(16) float2 sm_pl[RR * KK];  // 16384 B
    __shared__ float  sm_mass[PP * 36];              // 2304 B (pad 36: 16B-aligned rows)
    __shared__ float2 sm_plist[496];                 // 3968 B (omega, rs) — lives pre..ph5
    __shared__ float  sm_cc[RR];                     // 128 B
    __shared__ float  sm_sw[PP];                     // 64 B
    __shared__ float  sred[4];
    __shared__ int    cnt;

    float2* sm_cT2 = sm_pl;                  // 32*33 float2 = 8448 B
    float*  sm_m   = (float*)sm_pl + 2112;   // byte offset 8448, 4096 B (16B-aligned)

    const int tid = threadIdx.x;
    const int bt  = blockIdx.x;
    const int kq  = tid & 63;

    // ---- stage: c transposed (4 KB), m tile (4 KB coalesced float4), w ----
    {
        const float2* c2 = (const float2*)c;  // [r][d2], 1024 entries
#pragma unroll
        for (int it = 0; it < 4; ++it) {
            int idx = tid + 256 * it;
            sm_cT2[(idx & 31) * 33 + (idx >> 5)] = c2[idx];
        }
        const float4* m4 = (const float4*)(m + (size_t)bt * PP * DD);
        ((float4*)sm_m)[tid] = m4[tid];
        if (tid < PP) sm_sw[tid] = w[(size_t)bt * PP + tid];
        if (tid == 0) cnt = 0;
    }
    __syncthreads();  // B1

    // ---- pre-phase: local prune. Thread (r0 = tid>>5, s = tid&31) handles pairs
    //      (r0 + 8k, s), k = 0..3. ca broadcast per half-wave; cb 2-way (free). ----
    const int s_ = tid & 31, r0_ = tid >> 5;
    float d2k[4] = {0.f, 0.f, 0.f, 0.f};
    float a2 = 0.f;
#pragma unroll
    for (int i = 0; i < 32; ++i) {
        float2 cb = sm_cT2[i * 33 + s_];
        a2 = fmaf(cb.x, cb.x, a2);
        a2 = fmaf(cb.y, cb.y, a2);
#pragma unroll
        for (int k = 0; k < 4; ++k) {
            float2 ca = sm_cT2[i * 33 + r0_ + 8 * k];
            float dx = ca.x - cb.x, dy = ca.y - cb.y;
            d2k[k] = fmaf(dx, dx, d2k[k]);
            d2k[k] = fmaf(dy, dy, d2k[k]);
        }
    }
    if (tid < RR) sm_cc[tid] = a2;  // tid<32 -> s_=tid, column norm = ||c_s||^2

    float dm = 3.4e38f;
#pragma unroll
    for (int k = 0; k < 4; ++k) if (r0_ + 8 * k < s_) dm = fminf(dm, d2k[k]);
#pragma unroll
    for (int off = 32; off > 0; off >>= 1) dm = fminf(dm, __shfl_down(dm, off, 64));
    if ((tid & 63) == 0) sred[tid >> 6] = dm;
    __syncthreads();  // B2
    const float dmin = fminf(fminf(sred[0], sred[1]), fminf(sred[2], sred[3]));

    // ---- compaction into LDS plist (order nondet; sum reorder only moves rounding) ----
#pragma unroll
    for (int k = 0; k < 4; ++k) {
        int r = r0_ + 8 * k;
        if (r < s_ && d2k[k] <= dmin + D2_CUT) {
            int idx = atomicAdd(&cnt, 1);
            sm_plist[idx] = make_float2(fast_exp2(-d2k[k] * LOG2E),
                                        __int_as_float(r * 32 + s_));
        }
    }

    // ---- phase 1: logits[p][r] = 2*m.c - ||c||^2 (||m||^2 cancels in softmax).
    //      Same barrier region as compaction (independent work). ----
    {
        const int r  = tid & 31;
        const int pg = tid >> 5;  // 0..7; handles pi = pg and pg+8
        const float4* m4a = (const float4*)(sm_m + pg * DD);
        const float4* m4b = (const float4*)(sm_m + (pg + 8) * DD);
        float ccr = sm_cc[r];
        float acc0 = 0.f, acc1 = 0.f;
#pragma unroll
        for (int d4 = 0; d4 < 16; ++d4) {
            float2 ca = sm_cT2[(2 * d4) * 33 + r];
            float2 cb = sm_cT2[(2 * d4 + 1) * 33 + r];
            float4 ma = m4a[d4];
            float4 mb = m4b[d4];
            acc0 = fmaf(ma.x, ca.x, acc0); acc0 = fmaf(ma.y, ca.y, acc0);
            acc0 = fmaf(ma.z, cb.x, acc0); acc0 = fmaf(ma.w, cb.y, acc0);
            acc1 = fmaf(mb.x, ca.x, acc1); acc1 = fmaf(mb.y, ca.y, acc1);
            acc1 = fmaf(mb.z, cb.x, acc1); acc1 = fmaf(mb.w, cb.y, acc1);
        }
        sm_mass[pg * 36 + r]       = fmaf(2.f, acc0, -ccr);
        sm_mass[(pg + 8) * 36 + r] = fmaf(2.f, acc1, -ccr);
    }
    __syncthreads();  // B3

    // ---- phase 2: per-p softmax over r, all 256 threads.
    //      16 lanes per p, 2 r each; shfl_xor reduce within 16-lane groups. ----
    {
        const int pidx = tid >> 4, l = tid & 15;
        float a = sm_mass[pidx * 36 + l];
        float b = sm_mass[pidx * 36 + l + 16];
        float mx = fmaxf(a, b);
#pragma unroll
        for (int off = 8; off > 0; off >>= 1) mx = fmaxf(mx, __shfl_xor(mx, off, 64));
        float ea = fast_exp2((a - mx) * LOG2E);
        float eb = fast_exp2((b - mx) * LOG2E);
        float ssum = ea + eb;
#pragma unroll
        for (int off = 8; off > 0; off >>= 1) ssum += __shfl_xor(ssum, off, 64);
        sm_mass[pidx * 36 + l]      = ea;
        sm_mass[pidx * 36 + l + 16] = eb;
        if (l == 0) sm_sw[pidx] = sm_sw[pidx] * fast_rcp(ssum);  // w / sum
    }
    __syncthreads();  // B4

    // ---- phase 3: mass[p][r] = e*sw[p] / (tot_r + eps); one full wave ----
    if (tid < 64) {
        const int r = tid & 31, h = tid >> 5;
        float ef[8];
        float tot = 0.f;
#pragma unroll
        for (int i = 0; i < 8; ++i) {
            ef[i] = sm_mass[(h * 8 + i) * 36 + r] * sm_sw[h * 8 + i];
            tot += ef[i];
        }
        tot += __shfl_xor(tot, 32, 64);
        float inv = fast_rcp(tot + 1e-6f);
#pragma unroll
        for (int i = 0; i < 8; ++i) sm_mass[(h * 8 + i) * 36 + r] = ef[i] * inv;
    }
    __syncthreads();  // B5

    // ---- phase 4: pbar[r][k]; store (pb, pb*log2 pb); overwrites cT2/m (dead) ----
    {
        const int wv = tid >> 6;
        const int r0 = wv * 8;
        const float* pg_ = p + (size_t)bt * PP * KK + kq;
        float pcol[PP];
#pragma unroll
        for (int pi = 0; pi < PP; ++pi) pcol[pi] = pg_[pi * KK];
        float acc[8] = {0.f, 0.f, 0.f, 0.f, 0.f, 0.f, 0.f, 0.f};
#pragma unroll
        for (int pi = 0; pi < PP; ++pi) {
            float4 ma = *(const float4*)&sm_mass[pi * 36 + r0];      // wave-uniform bcast
            float4 mb = *(const float4*)&sm_mass[pi * 36 + r0 + 4];
            acc[0] = fmaf(pcol[pi], ma.x, acc[0]);
            acc[1] = fmaf(pcol[pi], ma.y, acc[1]);
            acc[2] = fmaf(pcol[pi], ma.z, acc[2]);
            acc[3] = fmaf(pcol[pi], ma.w, acc[3]);
            acc[4] = fmaf(pcol[pi], mb.x, acc[4]);
            acc[5] = fmaf(pcol[pi], mb.y, acc[5]);
            acc[6] = fmaf(pcol[pi], mb.z, acc[6]);
            acc[7] = fmaf(pcol[pi], mb.w, acc[7]);
        }
#pragma unroll
        for (int j = 0; j < 8; ++j) {
            float pb = acc[j];
            float l2 = fast_log2(pb + 1e-8f);
            sm_pl[(r0 + j) * KK + kq] = make_float2(pb, pb * l2);
        }
    }
    __syncthreads();  // B6

    // ---- phase 5: sum over pruned pairs of omega*[pr*l2pr + ps*l2ps - (pr+ps)*l2(mid)];
    //      plist now in LDS (wave-uniform -> broadcast); 2 pairs/iter for ILP ----
    {
        const int wv = __builtin_amdgcn_readfirstlane(tid >> 6);
        const int np = cnt;
        float acc = 0.f;
        int i = wv;
        for (; i + 4 < np; i += 8) {
            float2 e0 = sm_plist[i];
            float2 e1 = sm_plist[i + 4];
            int rs0 = __float_as_int(e0.y);
            int rs1 = __float_as_int(e1.y);
            float2 a0 = sm_pl[(rs0 >> 5) * KK + kq];
            float2 b0 = sm_pl[(rs0 & 31) * KK + kq];
            float2 a1 = sm_pl[(rs1 >> 5) * KK + kq];
            float2 b1 = sm_pl[(rs1 & 31) * KK + kq];
            float s0 = a0.x + b0.x, t0 = a0.y + b0.y;
            float s1 = a1.x + b1.x, t1 = a1.y + b1.y;
            float lm0 = fast_log2(fmaf(0.5f, s0, 1e-8f));
            float lm1 = fast_log2(fmaf(0.5f, s1, 1e-8f));
            t0 = fmaf(-s0, lm0, t0);
            t1 = fmaf(-s1, lm1, t1);
            acc = fmaf(e0.x, t0, acc);
            acc = fmaf(e1.x, t1, acc);
        }
        if (i < np) {
            float2 e = sm_plist[i];
            int rs = __float_as_int(e.y);
            float2 a = sm_pl[(rs >> 5) * KK + kq];
            float2 b = sm_pl[(rs & 31) * KK + kq];
            float sum = a.x + b.x;
            float t   = a.y + b.y;
            float lm  = fast_log2(fmaf(0.5f, sum, 1e-8f));
            t = fmaf(-sum, lm, t);
            acc = fmaf(e.x, t, acc);
        }
#pragma unroll
        for (int off = 32; off > 0; off >>= 1) acc += __shfl_down(acc, off, 64);
        if (kq == 0) sred[tid >> 6] = acc;
    }
    __syncthreads();
    if (tid == 0) {
        float tot = (sred[0] + sred[1]) + (sred[2] + sred[3]);
        partials[bt] = tot * (0.5f * LN2 / 496.0f);  // plain store, no atomic
    }
}

__global__ __launch_bounds__(256) void reduce_kernel(const float* __restrict__ partials,
                                                     float* __restrict__ out) {
    __shared__ float sred[4];
    const int tid = threadIdx.x;
    const float4* p4 = (const float4*)partials;  // 1024 float4
    float acc = 0.f;
#pragma unroll
    for (int i = 0; i < 4; ++i) {
        float4 v = p4[tid + 256 * i];
        acc += (v.x + v.y) + (v.z + v.w);
    }
#pragma unroll
    for (int off = 32; off > 0; off >>= 1) acc += __shfl_down(acc, off, 64);
    if ((tid & 63) == 0) sred[tid >> 6] = acc;
    __syncthreads();
    if (tid == 0) out[0] = (sred[0] + sred[1]) + (sred[2] + sred[3]);
}

extern "C" void kernel_launch(void* const* d_in, const int* in_sizes, int n_in,
                              void* d_out, int out_size, void* d_ws, size_t ws_size,
                              hipStream_t stream) {
    const float* m = (const float*)d_in[0];
    const float* w = (const float*)d_in[1];
    const float* p = (const float*)d_in[2];
    const float* c = (const float*)d_in[3];
    float* out = (float*)d_out;

    float* partials = (float*)d_ws;  // 4096 floats, 16 KB, 16B-aligned

    sheaf_kernel<<<NBT, 256, 0, stream>>>(m, w, p, c, partials);
    reduce_kernel<<<1, 256, 0, stream>>>(partials, out);
}

// Round 4
// 100.896 us; speedup vs baseline: 1.8465x; 1.8465x over previous
//
#include <hip/hip_runtime.h>

#define PP 16
#define DD 64
#define RR 32
#define KK 64
#define NBT 4096   // B*T

#define LOG2E 1.4426950408889634f
#define LN2   0.6931471805599453f
#define D2_CUT 25.0f   // keep pairs with d2 <= d2min + CUT; error <= omega_max*e^-25*ln2

static __device__ __forceinline__ float fast_log2(float x) { return __builtin_amdgcn_logf(x); }
static __device__ __forceinline__ float fast_exp2(float x) { return __builtin_amdgcn_exp2f(x); }
static __device__ __forceinline__ float fast_rcp(float x)  { return __builtin_amdgcn_rcpf(x); }

// One block, 1024 threads: thread t=(r,s). Stages c into LDS (transposed, padded),
// computes cc[r]=||c_r||^2, finds d2min over r<s, compacts pairs with
// d2 <= d2min+CUT into plist as (omega, int(r*32+s)).
__global__ __launch_bounds__(1024) void prune_kernel(const float* __restrict__ c,
                                                     float* __restrict__ cc,
                                                     int* __restrict__ npairs,
                                                     float2* __restrict__ plist) {
    __shared__ float2 sm_cT2[32 * 33];   // [d2][r], pad 33 -> conflict-free
    __shared__ float red[16];
    __shared__ float dmin_sh;
    __shared__ int cnt;
    const int t = threadIdx.x;

    // stage c transposed: c2 is [r][d2] (32x32 float2), one entry per thread
    {
        const float2* c2 = (const float2*)c;
        int rr = t >> 5, d2i = t & 31;
        sm_cT2[d2i * 33 + rr] = c2[t];
    }
    if (t == 0) cnt = 0;
    __syncthreads();

    const int r = t >> 5, s = t & 31;
    const bool active = s > r;
    float d2 = 0.f;
#pragma unroll
    for (int i = 0; i < 32; ++i) {
        float2 ca = sm_cT2[i * 33 + r];   // broadcast within half-wave
        float2 cb = sm_cT2[i * 33 + s];   // contiguous, 2-way (free)
        float dx = ca.x - cb.x, dy = ca.y - cb.y;
        d2 = fmaf(dx, dx, d2);
        d2 = fmaf(dy, dy, d2);
    }
    float dm = active ? d2 : 3.4e38f;
#pragma unroll
    for (int off = 32; off > 0; off >>= 1) dm = fminf(dm, __shfl_down(dm, off, 64));
    if ((t & 63) == 0) red[t >> 6] = dm;
    __syncthreads();
    if (t < 64) {
        float v = (t < 16) ? red[t] : 3.4e38f;
#pragma unroll
        for (int off = 8; off > 0; off >>= 1) v = fminf(v, __shfl_down(v, off, 64));
        if (t == 0) dmin_sh = v;
    }
    if (t < RR) {  // cc from LDS
        float a2 = 0.f;
#pragma unroll
        for (int i = 0; i < 32; ++i) {
            float2 cv = sm_cT2[i * 33 + t];
            a2 = fmaf(cv.x, cv.x, a2);
            a2 = fmaf(cv.y, cv.y, a2);
        }
        cc[t] = a2;
    }
    __syncthreads();
    const float dmin = dmin_sh;
    if (active && d2 <= dmin + D2_CUT) {
        int idx = atomicAdd(&cnt, 1);
        plist[idx] = make_float2(fast_exp2(-d2 * LOG2E), __int_as_float(t));
    }
    __syncthreads();
    if (t == 0) *npairs = cnt;
}

// Round-4 isolation: EXACTLY round-2's kernel body, but the 4096-block
// single-address atomicAdd (suspected ~25 us far-atomic drain) is replaced by a
// plain partials[bt] store + separate 1-block reduce (round-0-proven). pcol
// entry prefetch restored (natural VGPR allocation -> no spills; r1's spills
// were from the forced 32-VGPR launch-bounds cap, not the prefetch).
__global__ __launch_bounds__(256) void sheaf2_kernel(
    const float* __restrict__ m, const float* __restrict__ w,
    const float* __restrict__ p, const float* __restrict__ c,
    const float* __restrict__ cc, const int* __restrict__ npairs,
    const float2* __restrict__ plist, float* __restrict__ partials) {
    // Alias zone: sm_pl (phase 4/5) overlaps cT2 (bytes 0-8447, phases 0-1) and
    // the staged m tile (bytes 8448-12543, phase 1). Lifetimes barrier-separated.
    __shared__ __align__(16) float2 sm_pl[RR * KK];  // 16384 B
    __shared__ float  sm_mass[PP * 36];              // 2304 B (pad 36: 16B-aligned rows)
    __shared__ float  sm_sw[PP];
    __shared__ float  sred[4];

    float2* sm_cT2 = sm_pl;                  // 32*33 float2 = 8448 B
    float*  sm_m   = (float*)sm_pl + 2112;   // byte offset 8448, 4096 B (16B-aligned)

    const int tid = threadIdx.x;
    const int bt  = blockIdx.x;
    const int kq  = tid & 63;

    // ---- entry prefetch: p column (16 regs) + np; latency hides under phases 1-3 ----
    const float* pg_ = p + (size_t)bt * PP * KK + kq;
    float pcol[PP];
#pragma unroll
    for (int pi = 0; pi < PP; ++pi) pcol[pi] = pg_[pi * KK];
    const int np = __builtin_amdgcn_readfirstlane(*npairs);

    // ---- stage: c transposed (4 KB), m tile (4 KB coalesced float4), w ----
    {
        const float2* c2 = (const float2*)c;  // [r][d2], 1024 entries
#pragma unroll
        for (int it = 0; it < 4; ++it) {
            int idx = tid + 256 * it;
            sm_cT2[(idx & 31) * 33 + (idx >> 5)] = c2[idx];
        }
        const float4* m4 = (const float4*)(m + (size_t)bt * PP * DD);
        ((float4*)sm_m)[tid] = m4[tid];
        if (tid < PP) sm_sw[tid] = w[(size_t)bt * PP + tid];
    }
    __syncthreads();

    // ---- phase 1: logits[p][r] = 2*m.c - ||c||^2 (||m||^2 cancels in softmax).
    //      m rows from LDS (wave-uniform addr -> broadcast, no VMEM). ----
    {
        const int r  = tid & 31;
        const int pg = tid >> 5;  // 0..7; handles pi = pg and pg+8
        const float4* m4a = (const float4*)(sm_m + pg * DD);
        const float4* m4b = (const float4*)(sm_m + (pg + 8) * DD);
        float ccr = cc[r];
        float acc0 = 0.f, acc1 = 0.f;
#pragma unroll
        for (int d4 = 0; d4 < 16; ++d4) {
            float2 ca = sm_cT2[(2 * d4) * 33 + r];
            float2 cb = sm_cT2[(2 * d4 + 1) * 33 + r];
            float4 ma = m4a[d4];
            float4 mb = m4b[d4];
            acc0 = fmaf(ma.x, ca.x, acc0); acc0 = fmaf(ma.y, ca.y, acc0);
            acc0 = fmaf(ma.z, cb.x, acc0); acc0 = fmaf(ma.w, cb.y, acc0);
            acc1 = fmaf(mb.x, ca.x, acc1); acc1 = fmaf(mb.y, ca.y, acc1);
            acc1 = fmaf(mb.z, cb.x, acc1); acc1 = fmaf(mb.w, cb.y, acc1);
        }
        sm_mass[pg * 36 + r]       = fmaf(2.f, acc0, -ccr);
        sm_mass[(pg + 8) * 36 + r] = fmaf(2.f, acc1, -ccr);
    }
    __syncthreads();

    // ---- phase 2: per-p softmax over r, all 256 threads.
    //      16 lanes per p, 2 r each; shfl_xor reduce within 16-lane groups. ----
    {
        const int pidx = tid >> 4, l = tid & 15;
        float a = sm_mass[pidx * 36 + l];
        float b = sm_mass[pidx * 36 + l + 16];
        float mx = fmaxf(a, b);
#pragma unroll
        for (int off = 8; off > 0; off >>= 1) mx = fmaxf(mx, __shfl_xor(mx, off, 64));
        float ea = fast_exp2((a - mx) * LOG2E);
        float eb = fast_exp2((b - mx) * LOG2E);
        float ssum = ea + eb;
#pragma unroll
        for (int off = 8; off > 0; off >>= 1) ssum += __shfl_xor(ssum, off, 64);
        sm_mass[pidx * 36 + l]      = ea;
        sm_mass[pidx * 36 + l + 16] = eb;
        if (l == 0) sm_sw[pidx] = sm_sw[pidx] * fast_rcp(ssum);  // w / sum
    }
    __syncthreads();

    // ---- phase 3: mass[p][r] = e*sw[p] / (tot_r + eps); one full wave ----
    if (tid < 64) {
        const int r = tid & 31, h = tid >> 5;
        float ef[8];
        float tot = 0.f;
#pragma unroll
        for (int i = 0; i < 8; ++i) {
            ef[i] = sm_mass[(h * 8 + i) * 36 + r] * sm_sw[h * 8 + i];
            tot += ef[i];
        }
        tot += __shfl_xor(tot, 32, 64);
        float inv = fast_rcp(tot + 1e-6f);
#pragma unroll
        for (int i = 0; i < 8; ++i) sm_mass[(h * 8 + i) * 36 + r] = ef[i] * inv;
    }
    __syncthreads();

    // ---- phase 4: pbar[r][k]; store (pb, pb*log2 pb); overwrites cT2/m (dead) ----
    {
        const int wv = tid >> 6;
        const int r0 = wv * 8;
        float acc[8] = {0.f, 0.f, 0.f, 0.f, 0.f, 0.f, 0.f, 0.f};
#pragma unroll
        for (int pi = 0; pi < PP; ++pi) {
            float4 ma = *(const float4*)&sm_mass[pi * 36 + r0];      // wave-uniform bcast
            float4 mb = *(const float4*)&sm_mass[pi * 36 + r0 + 4];
            acc[0] = fmaf(pcol[pi], ma.x, acc[0]);
            acc[1] = fmaf(pcol[pi], ma.y, acc[1]);
            acc[2] = fmaf(pcol[pi], ma.z, acc[2]);
            acc[3] = fmaf(pcol[pi], ma.w, acc[3]);
            acc[4] = fmaf(pcol[pi], mb.x, acc[4]);
            acc[5] = fmaf(pcol[pi], mb.y, acc[5]);
            acc[6] = fmaf(pcol[pi], mb.z, acc[6]);
            acc[7] = fmaf(pcol[pi], mb.w, acc[7]);
        }
#pragma unroll
        for (int j = 0; j < 8; ++j) {
            float pb = acc[j];
            float l2 = fast_log2(pb + 1e-8f);
            sm_pl[(r0 + j) * KK + kq] = make_float2(pb, pb * l2);
        }
    }
    __syncthreads();

    // ---- phase 5: sum over pruned pairs of omega*[pr*l2pr + ps*l2ps - (pr+ps)*l2(mid)];
    //      plist loads wave-uniform -> s_load; 2 pairs/iter for ILP ----
    {
        const int wv = __builtin_amdgcn_readfirstlane(tid >> 6);
        float acc = 0.f;
        int i = wv;
        for (; i + 4 < np; i += 8) {
            float2 e0 = plist[i];
            float2 e1 = plist[i + 4];
            int rs0 = __float_as_int(e0.y);
            int rs1 = __float_as_int(e1.y);
            float2 a0 = sm_pl[(rs0 >> 5) * KK + kq];
            float2 b0 = sm_pl[(rs0 & 31) * KK + kq];
            float2 a1 = sm_pl[(rs1 >> 5) * KK + kq];
            float2 b1 = sm_pl[(rs1 & 31) * KK + kq];
            float s0 = a0.x + b0.x, t0 = a0.y + b0.y;
            float s1 = a1.x + b1.x, t1 = a1.y + b1.y;
            float lm0 = fast_log2(fmaf(0.5f, s0, 1e-8f));
            float lm1 = fast_log2(fmaf(0.5f, s1, 1e-8f));
            t0 = fmaf(-s0, lm0, t0);
            t1 = fmaf(-s1, lm1, t1);
            acc = fmaf(e0.x, t0, acc);
            acc = fmaf(e1.x, t1, acc);
        }
        if (i < np) {
            float2 e = plist[i];
            int rs = __float_as_int(e.y);
            float2 a = sm_pl[(rs >> 5) * KK + kq];
            float2 b = sm_pl[(rs & 31) * KK + kq];
            float sum = a.x + b.x;
            float t   = a.y + b.y;
            float lm  = fast_log2(fmaf(0.5f, sum, 1e-8f));
            t = fmaf(-sum, lm, t);
            acc = fmaf(e.x, t, acc);
        }
#pragma unroll
        for (int off = 32; off > 0; off >>= 1) acc += __shfl_down(acc, off, 64);
        if (kq == 0) sred[tid >> 6] = acc;
    }
    __syncthreads();
    if (tid == 0) {
        float tot = (sred[0] + sred[1]) + (sred[2] + sred[3]);
        partials[bt] = tot * (0.5f * LN2 / 496.0f);  // plain store, no atomic
    }
}

__global__ __launch_bounds__(256) void reduce_kernel(const float* __restrict__ partials,
                                                     float* __restrict__ out) {
    __shared__ float sred[4];
    const int tid = threadIdx.x;
    const float4* p4 = (const float4*)partials;  // 1024 float4
    float acc = 0.f;
#pragma unroll
    for (int i = 0; i < 4; ++i) {
        float4 v = p4[tid + 256 * i];
        acc += (v.x + v.y) + (v.z + v.w);
    }
#pragma unroll
    for (int off = 32; off > 0; off >>= 1) acc += __shfl_down(acc, off, 64);
    if ((tid & 63) == 0) sred[tid >> 6] = acc;
    __syncthreads();
    if (tid == 0) out[0] = (sred[0] + sred[1]) + (sred[2] + sred[3]);
}

extern "C" void kernel_launch(void* const* d_in, const int* in_sizes, int n_in,
                              void* d_out, int out_size, void* d_ws, size_t ws_size,
                              hipStream_t stream) {
    const float* m = (const float*)d_in[0];
    const float* w = (const float*)d_in[1];
    const float* p = (const float*)d_in[2];
    const float* c = (const float*)d_in[3];
    float* out = (float*)d_out;

    float* wsf      = (float*)d_ws;
    int*   npairs   = (int*)d_ws;            // [0]
    float* cc       = wsf + 64;              // 32 floats @ 256 B
    float2* plist   = (float2*)(wsf + 128);  // up to 496 float2 @ 512 B
    float* partials = wsf + 2048;            // 4096 floats @ 8 KB (16B-aligned)

    prune_kernel<<<1, 1024, 0, stream>>>(c, cc, npairs, plist);
    sheaf2_kernel<<<NBT, 256, 0, stream>>>(m, w, p, c, cc, npairs, plist, partials);
    reduce_kernel<<<1, 256, 0, stream>>>(partials, out);
}

// Round 5
// 100.045 us; speedup vs baseline: 1.8622x; 1.0085x over previous
//
#include <hip/hip_runtime.h>

#define PP 16
#define DD 64
#define RR 32
#define KK 64
#define NBT 4096   // B*T

#define LOG2E 1.4426950408889634f
#define LN2   0.6931471805599453f
#define D2_CUT 25.0f   // keep pairs with d2 <= d2min + CUT; error <= omega_max*e^-25*ln2

static __device__ __forceinline__ float fast_log2(float x) { return __builtin_amdgcn_logf(x); }
static __device__ __forceinline__ float fast_exp2(float x) { return __builtin_amdgcn_exp2f(x); }
static __device__ __forceinline__ float fast_rcp(float x)  { return __builtin_amdgcn_rcpf(x); }

// Wave-internal phase fence: drains this wave's LDS ops (lgkmcnt counts the whole
// wave's outstanding DS ops; all 64 lanes share one instruction stream, so
// program order + lgkmcnt(0) makes cross-lane LDS writes visible). "memory"
// clobber stops the compiler moving DS ops across it. No s_barrier needed.
#define WAVE_SYNC() asm volatile("s_waitcnt lgkmcnt(0)" ::: "memory")

// One block, 1024 threads: thread t=(r,s). Stages c into LDS (transposed, padded),
// computes cc[r]=||c_r||^2, finds d2min over r<s, compacts pairs with
// d2 <= d2min+CUT into plist as (omega, int(r*32+s)).
__global__ __launch_bounds__(1024) void prune_kernel(const float* __restrict__ c,
                                                     float* __restrict__ cc,
                                                     int* __restrict__ npairs,
                                                     float2* __restrict__ plist) {
    __shared__ float2 sm_cT2[32 * 33];   // [d2][r], pad 33 -> conflict-free
    __shared__ float red[16];
    __shared__ float dmin_sh;
    __shared__ int cnt;
    const int t = threadIdx.x;

    {
        const float2* c2 = (const float2*)c;
        int rr = t >> 5, d2i = t & 31;
        sm_cT2[d2i * 33 + rr] = c2[t];
    }
    if (t == 0) cnt = 0;
    __syncthreads();

    const int r = t >> 5, s = t & 31;
    const bool active = s > r;
    float d2 = 0.f;
#pragma unroll
    for (int i = 0; i < 32; ++i) {
        float2 ca = sm_cT2[i * 33 + r];
        float2 cb = sm_cT2[i * 33 + s];
        float dx = ca.x - cb.x, dy = ca.y - cb.y;
        d2 = fmaf(dx, dx, d2);
        d2 = fmaf(dy, dy, d2);
    }
    float dm = active ? d2 : 3.4e38f;
#pragma unroll
    for (int off = 32; off > 0; off >>= 1) dm = fminf(dm, __shfl_down(dm, off, 64));
    if ((t & 63) == 0) red[t >> 6] = dm;
    __syncthreads();
    if (t < 64) {
        float v = (t < 16) ? red[t] : 3.4e38f;
#pragma unroll
        for (int off = 8; off > 0; off >>= 1) v = fminf(v, __shfl_down(v, off, 64));
        if (t == 0) dmin_sh = v;
    }
    if (t < RR) {
        float a2 = 0.f;
#pragma unroll
        for (int i = 0; i < 32; ++i) {
            float2 cv = sm_cT2[i * 33 + t];
            a2 = fmaf(cv.x, cv.x, a2);
            a2 = fmaf(cv.y, cv.y, a2);
        }
        cc[t] = a2;
    }
    __syncthreads();
    const float dmin = dmin_sh;
    if (active && d2 <= dmin + D2_CUT) {
        int idx = atomicAdd(&cnt, 1);
        plist[idx] = make_float2(fast_exp2(-d2 * LOG2E), __int_as_float(t));
    }
    __syncthreads();
    if (t == 0) *npairs = cnt;
}

// Wave-per-bt: 4 waves/block, each wave processes one bt end-to-end with ZERO
// block barriers after staging. All inter-phase dataflow is wave-internal LDS
// (WAVE_SYNC = lgkmcnt fence). LDS 51.7 KB -> 3 blocks/CU = 12 fully
// independent waves/CU. launch_bounds(256,3) caps VGPR at 168 (natural ~90).
__global__ __launch_bounds__(256, 3) void sheaf3_kernel(
    const float* __restrict__ m, const float* __restrict__ w,
    const float* __restrict__ p, const float* __restrict__ c,
    const float* __restrict__ cc, const int* __restrict__ npairs,
    const float2* __restrict__ plist, float* __restrict__ partials) {
    __shared__ float2 sm_cT2[32 * 33];                 // 8448 B, shared, read-only
    __shared__ __align__(16) float sm_pl[4][2048];     // 8 KB/wave: m-stage then pb[r][k]
    __shared__ __align__(16) float sm_scr[4][640];     // 2.5 KB/wave: logits->exp->massT
    __shared__ float sm_sw4[4][16];                    // 64 B/wave

    const int tid = threadIdx.x;
    const int wv  = tid >> 6;
    const int ln  = tid & 63;
    const int bt  = blockIdx.x * 4 + wv;

    float* pl  = sm_pl[wv];
    float* scr = sm_scr[wv];
    float* swv = sm_sw4[wv];

    const int r_ = ln & 31, h_ = ln >> 5;  // phase 1/3 mapping
    const int k  = ln;                     // phase 4/5 mapping

    // ---- entry prefetches (latency hides under staging + phase 1) ----
    const float* pg_ = p + (size_t)bt * PP * KK + k;
    float pcol[PP];
#pragma unroll
    for (int pi = 0; pi < PP; ++pi) pcol[pi] = pg_[pi * KK];
    const int np = __builtin_amdgcn_readfirstlane(*npairs);
    const float ccr  = cc[r_];
    const float wreg = w[(size_t)bt * PP + (ln >> 2)];  // used by q==0 lanes in ph2

    // ---- stage: cT2 cooperative (shared); m tile per wave into its pl region ----
    {
        const float2* c2 = (const float2*)c;
#pragma unroll
        for (int it = 0; it < 4; ++it) {
            int idx = tid + 256 * it;
            sm_cT2[(idx & 31) * 33 + (idx >> 5)] = c2[idx];
        }
        const float4* m4g = (const float4*)(m + (size_t)bt * PP * DD);
        float4* m4l = (float4*)pl;
#pragma unroll
        for (int it = 0; it < 4; ++it) m4l[ln + 64 * it] = m4g[ln + 64 * it];
    }
    __syncthreads();  // the ONLY block barrier (cT2 + per-wave m visibility)

    // ---- phase 1: logits[p][r] = 2*m.c - ||c||^2. Lane (h_, r_) does p = h_*8+i.
    //      m reads: 2-distinct-addr LDS broadcast; c reads shared cT2. ----
    {
        const float* mw = pl;  // [p][64] view of staged m
        float acc[8] = {0.f, 0.f, 0.f, 0.f, 0.f, 0.f, 0.f, 0.f};
#pragma unroll
        for (int d4 = 0; d4 < 16; ++d4) {
            float2 ca = sm_cT2[(2 * d4) * 33 + r_];
            float2 cb = sm_cT2[(2 * d4 + 1) * 33 + r_];
#pragma unroll
            for (int i = 0; i < 8; ++i) {
                float4 mm = *(const float4*)(mw + (h_ * 8 + i) * DD + d4 * 4);
                acc[i] = fmaf(mm.x, ca.x, acc[i]);
                acc[i] = fmaf(mm.y, ca.y, acc[i]);
                acc[i] = fmaf(mm.z, cb.x, acc[i]);
                acc[i] = fmaf(mm.w, cb.y, acc[i]);
            }
        }
#pragma unroll
        for (int i = 0; i < 8; ++i)
            scr[(h_ * 8 + i) * 36 + r_] = fmaf(2.f, acc[i], -ccr);  // [p][36] view
    }
    WAVE_SYNC();

    // ---- phase 2: softmax over r per p. Lane (pq = ln>>2, q = ln&3) owns 8 r's;
    //      4-lane-group reduce via shfl_xor(1,2). ----
    {
        const int pq = ln >> 2, q = ln & 3;
        float4 v0 = *(const float4*)(scr + pq * 36 + q * 8);
        float4 v1 = *(const float4*)(scr + pq * 36 + q * 8 + 4);
        float mx = fmaxf(fmaxf(fmaxf(v0.x, v0.y), fmaxf(v0.z, v0.w)),
                         fmaxf(fmaxf(v1.x, v1.y), fmaxf(v1.z, v1.w)));
        mx = fmaxf(mx, __shfl_xor(mx, 1, 64));
        mx = fmaxf(mx, __shfl_xor(mx, 2, 64));
        v0.x = fast_exp2((v0.x - mx) * LOG2E); v0.y = fast_exp2((v0.y - mx) * LOG2E);
        v0.z = fast_exp2((v0.z - mx) * LOG2E); v0.w = fast_exp2((v0.w - mx) * LOG2E);
        v1.x = fast_exp2((v1.x - mx) * LOG2E); v1.y = fast_exp2((v1.y - mx) * LOG2E);
        v1.z = fast_exp2((v1.z - mx) * LOG2E); v1.w = fast_exp2((v1.w - mx) * LOG2E);
        float ssum = ((v0.x + v0.y) + (v0.z + v0.w)) + ((v1.x + v1.y) + (v1.z + v1.w));
        ssum += __shfl_xor(ssum, 1, 64);
        ssum += __shfl_xor(ssum, 2, 64);
        *(float4*)(scr + pq * 36 + q * 8)     = v0;
        *(float4*)(scr + pq * 36 + q * 8 + 4) = v1;
        if (q == 0) swv[pq] = wreg * fast_rcp(ssum);  // w / sum
    }
    WAVE_SYNC();

    // ---- phase 3: mass[p][r] = e*sw[p]/(tot_r+eps); write TRANSPOSED massT[r][20-pad].
    //      All 8 reads precede all 8 writes (source order; may-alias keeps it). ----
    {
        float ef[8];
        float tot = 0.f;
#pragma unroll
        for (int i = 0; i < 8; ++i) {
            ef[i] = scr[(h_ * 8 + i) * 36 + r_] * swv[h_ * 8 + i];
            tot += ef[i];
        }
        tot += __shfl_xor(tot, 32, 64);  // combine p-halves
        float inv = fast_rcp(tot + 1e-6f);
#pragma unroll
        for (int i = 0; i < 8; ++i)
            scr[r_ * 20 + h_ * 8 + i] = ef[i] * inv;  // massT view [32][20]
    }
    WAVE_SYNC();

    // ---- phase 4: pb[r][k] = sum_p pcol[p]*massT[r][p]. massT reads are
    //      wave-uniform b128 broadcasts; pl writes contiguous. Overwrites m (dead). ----
    {
#pragma unroll
        for (int r = 0; r < 32; ++r) {
            const float4* mt = (const float4*)(scr + r * 20);
            float4 a0 = mt[0], a1 = mt[1], a2 = mt[2], a3 = mt[3];
            float pb = 0.f;
            pb = fmaf(pcol[0],  a0.x, pb); pb = fmaf(pcol[1],  a0.y, pb);
            pb = fmaf(pcol[2],  a0.z, pb); pb = fmaf(pcol[3],  a0.w, pb);
            pb = fmaf(pcol[4],  a1.x, pb); pb = fmaf(pcol[5],  a1.y, pb);
            pb = fmaf(pcol[6],  a1.z, pb); pb = fmaf(pcol[7],  a1.w, pb);
            pb = fmaf(pcol[8],  a2.x, pb); pb = fmaf(pcol[9],  a2.y, pb);
            pb = fmaf(pcol[10], a2.z, pb); pb = fmaf(pcol[11], a2.w, pb);
            pb = fmaf(pcol[12], a3.x, pb); pb = fmaf(pcol[13], a3.y, pb);
            pb = fmaf(pcol[14], a3.z, pb); pb = fmaf(pcol[15], a3.w, pb);
            pl[r * KK + k] = pb;
        }
    }
    WAVE_SYNC();

    // ---- phase 5: JS over pruned pairs; all 64 lanes (lane = k) iterate all np.
    //      3 logs per pair (np is small: ~10-30), saves the 2048-entry pl2 precompute. ----
    {
        float acc = 0.f;
        for (int i = 0; i < np; ++i) {
            float2 e = plist[i];  // wave-uniform -> s_load
            int rs = __float_as_int(e.y);
            float pa  = pl[(rs >> 5) * KK + k];
            float pbv = pl[(rs & 31) * KK + k];
            float sum = pa + pbv;
            float la = fast_log2(pa + 1e-8f);
            float lb = fast_log2(pbv + 1e-8f);
            float lm = fast_log2(fmaf(0.5f, sum, 1e-8f));
            float t = fmaf(pa, la, fmaf(pbv, lb, -sum * lm));
            acc = fmaf(e.x, t, acc);
        }
#pragma unroll
        for (int off = 32; off > 0; off >>= 1) acc += __shfl_down(acc, off, 64);
        if (k == 0) partials[bt] = acc * (0.5f * LN2 / 496.0f);
    }
}

__global__ __launch_bounds__(256) void reduce_kernel(const float* __restrict__ partials,
                                                     float* __restrict__ out) {
    __shared__ float sred[4];
    const int tid = threadIdx.x;
    const float4* p4 = (const float4*)partials;  // 1024 float4
    float acc = 0.f;
#pragma unroll
    for (int i = 0; i < 4; ++i) {
        float4 v = p4[tid + 256 * i];
        acc += (v.x + v.y) + (v.z + v.w);
    }
#pragma unroll
    for (int off = 32; off > 0; off >>= 1) acc += __shfl_down(acc, off, 64);
    if ((tid & 63) == 0) sred[tid >> 6] = acc;
    __syncthreads();
    if (tid == 0) out[0] = (sred[0] + sred[1]) + (sred[2] + sred[3]);
}

extern "C" void kernel_launch(void* const* d_in, const int* in_sizes, int n_in,
                              void* d_out, int out_size, void* d_ws, size_t ws_size,
                              hipStream_t stream) {
    const float* m = (const float*)d_in[0];
    const float* w = (const float*)d_in[1];
    const float* p = (const float*)d_in[2];
    const float* c = (const float*)d_in[3];
    float* out = (float*)d_out;

    float* wsf      = (float*)d_ws;
    int*   npairs   = (int*)d_ws;            // [0]
    float* cc       = wsf + 64;              // 32 floats @ 256 B
    float2* plist   = (float2*)(wsf + 128);  // up to 496 float2 @ 512 B
    float* partials = wsf + 2048;            // 4096 floats @ 8 KB (16B-aligned)

    prune_kernel<<<1, 1024, 0, stream>>>(c, cc, npairs, plist);
    sheaf3_kernel<<<NBT / 4, 256, 0, stream>>>(m, w, p, c, cc, npairs, plist, partials);
    reduce_kernel<<<1, 256, 0, stream>>>(partials, out);
}